// Round 2
// baseline (381.845 us; speedup 1.0000x reference)
//
#include <hip/hip_runtime.h>
#include <hip/hip_bf16.h>

// Problem constants (from reference): NV=4096, NH=4096, N=8192, h=0, p=1.
// Inputs: mu (f32, N), var (f32, N*N). Output: muTE (f32, N) ++ M (f32, N*N).
#define NN 8192

// ---------------------------------------------------------------------------
// Kernel 1: zero the entire output, 16B vector stores, grid-stride.
// out bytes = (NN + NN*NN)*4 = 268,468,224 B = 16,779,264 uint4.
// HBM-write roofline of the whole problem (~43 us @ 6.3 TB/s).
// ---------------------------------------------------------------------------
__global__ void zero_fill_kernel(uint4* __restrict__ out, long n16) {
    long i = (long)blockIdx.x * blockDim.x + threadIdx.x;
    long stride = (long)gridDim.x * blockDim.x;
    uint4 z; z.x = 0u; z.y = 0u; z.z = 0u; z.w = 0u;
    for (; i < n16; i += stride) out[i] = z;
}

// ---------------------------------------------------------------------------
// Kernel 2: write the non-zero structure (f32 throughout).
//   muTE[0]=hp, muTE[1]=-hp
//   M[0,j]=v[j], M[1,j]=-v[j]  (coalesced row writes)
//   M[j,0]=v[j], M[j,1]=-v[j]  for j>=2 (one 8B strided write per row)
//   2x2 block at (0,0),(0,1),(1,0),(1,1) from n3 special terms.
// v[j] = -2*mu[j]*mu1*mu0 + mu[j]*var[1,0] + mu1*var[j,0] + mu0*var[j,1],
// v[0]=v[1]=0.
// ---------------------------------------------------------------------------
__global__ void fixup_kernel(const float* __restrict__ mu,
                             const float* __restrict__ var,
                             float* __restrict__ out) {
    int j = blockIdx.x * blockDim.x + threadIdx.x;
    if (j >= NN) return;

    const long N = NN;
    float* M = out + N;  // M starts after muTE

    // Scalars (L1/L2-cached broadcast reads)
    float mu0   = mu[0];
    float mu1   = mu[1];
    float var00 = var[0];
    float var01 = var[1];      // hp = nvar[h,p]
    float var10 = var[N];      // nvar[p,h]
    float var11 = var[N + 1];
    float hp = var01;

    // v[j]
    float muj = mu[j];
    float vj0 = var[(long)j * N];      // nvar[j,h]
    float vj1 = var[(long)j * N + 1];  // nvar[j,p]
    float v = -2.0f * muj * mu1 * mu0 + muj * var10 + mu1 * vj0 + mu0 * vj1;
    if (j < 2) v = 0.0f;

    float r0, r1;  // values for M[0,j] and M[1,j]
    if (j == 0) {
        float n3_hhp = -2.0f * mu0 * mu0 * mu1 + 2.0f * mu0 * var01 + mu1 * var00;
        float n3_hpp = -2.0f * mu0 * mu1 * mu1 + mu0 * var11 + 2.0f * mu1 * var01;
        r0 = 2.0f * n3_hhp + hp;            // M[h,h]
        r1 = -n3_hhp + n3_hpp - hp;         // chp -> M[p,h]
        out[0] = hp;                        // muTE[h]
    } else if (j == 1) {
        float n3_hhp = -2.0f * mu0 * mu0 * mu1 + 2.0f * mu0 * var01 + mu1 * var00;
        float n3_hpp = -2.0f * mu0 * mu1 * mu1 + mu0 * var11 + 2.0f * mu1 * var01;
        float n3_pph = -2.0f * mu1 * mu1 * mu0 + 2.0f * mu1 * var10 + mu0 * var11;
        r0 = -n3_hhp + n3_hpp - hp;         // chp -> M[h,p]
        r1 = -2.0f * n3_pph + hp;           // M[p,p]
        out[1] = -hp;                       // muTE[p]
    } else {
        r0 = v;
        r1 = -v;
        // Column writes: M[j,0] and M[j,1] are adjacent f32 -> one 8B store.
        M[(long)j * N + 0] = v;
        M[(long)j * N + 1] = -v;
    }

    // Row writes (coalesced across the wave)
    M[j]     = r0;   // M[0,j]
    M[N + j] = r1;   // M[1,j]
}

extern "C" void kernel_launch(void* const* d_in, const int* in_sizes, int n_in,
                              void* d_out, int out_size, void* d_ws, size_t ws_size,
                              hipStream_t stream) {
    const float* mu  = (const float*)d_in[0];
    const float* var = (const float*)d_in[1];
    float* out = (float*)d_out;

    // Zero-fill entire output: (NN + NN*NN) f32 = 268,468,224 bytes,
    // divisible by 16 -> 16,779,264 uint4 stores.
    long n16 = ((long)NN + (long)NN * NN) * 4 / 16;
    zero_fill_kernel<<<8192, 256, 0, stream>>>((uint4*)out, n16);

    // Fix up non-zero entries.
    fixup_kernel<<<NN / 256, 256, 0, stream>>>(mu, var, out);
}